// Round 20
// baseline (91.337 us; speedup 1.0000x reference)
//
#include <hip/hip_runtime.h>
#include <math.h>

#define N_PTS 20000
#define M_ATM 8000
#define DD    16
#define KK    16
#define HH    33
#define BB    4
#define EPSGN 1e-5f
#define SLOPE 0.2f
#define SLOTS 36          // 36*64 = 2304 candidate slots per batch
#define PSLOT 2304
#define SENT  0xFFFFFFFFu // > any real key (real off <= 2303 < 0xFFF)

// packed layout per layer (floats): wx[33][20] | wb[33][16] | wt[33][16]
#define PK_WX   0
#define PK_WB   660
#define PK_WT   1188
#define PK_LAY  1716

// ws layout (bytes)
#define WS_PAD   0                      // 4*2304*16 = 147456 (padded f32 atom table)
#define WS_SEG   147456                 // 8 ints
#define WS_WP    147520                 // 3*1716 floats -> ends 168112
#define WS_IDX   168128                 // N*K ints
#define WS_D2    (168128 + 1280000)     // N*K floats

typedef __attribute__((ext_vector_type(2))) float f32x2;
__device__ __forceinline__ f32x2 mk2(float a, float b) { f32x2 r; r.x = a; r.y = b; return r; }
// packed fp32 FMA (VOP3P, 2 FMAs per issue slot on CDNA2+)
__device__ __forceinline__ void pkfma(f32x2& d, f32x2 a, f32x2 b) {
    asm("v_pk_fma_f32 %0, %1, %2, %0" : "+v"(d) : "v"(a), "v"(b));
}

// ---- DPP cross-lane helpers (VALU pipe, ~4cyc latency vs ~35 for ds_swizzle) ----
template<int CTRL> __device__ __forceinline__ float dpp_addf(float v) {
    return v + __int_as_float(__builtin_amdgcn_update_dpp(
        0, __float_as_int(v), CTRL, 0xF, 0xF, true));
}
__device__ __forceinline__ float dpp_sum16(float v) {
    v = dpp_addf<0xB1>(v);    // quad_perm xor1
    v = dpp_addf<0x4E>(v);    // quad_perm xor2
    v = dpp_addf<0x141>(v);   // row_half_mirror
    v = dpp_addf<0x140>(v);   // row_mirror
    return v;
}
__device__ __forceinline__ float dpp_sum8(float v) {
    v = dpp_addf<0xB1>(v);
    v = dpp_addf<0x4E>(v);
    v = dpp_addf<0x141>(v);
    return v;
}
// broadcast lane O (0..15) within each 16-lane group (BitMode swizzle)
template<int O> __device__ __forceinline__ float bc16(float v) {
    return __int_as_float(__builtin_amdgcn_ds_swizzle(
        __float_as_int(v), (O << 5) | 0x10));
}
template<int CTRL> __device__ __forceinline__ unsigned dpp_min_u32(unsigned v) {
    const unsigned o = (unsigned)__builtin_amdgcn_update_dpp(
        (int)v, (int)v, CTRL, 0xF, 0xF, false);
    return (o < v) ? o : v;
}
// median of 3 u32 (single VOP3) -- sorted-insert building block
__device__ __forceinline__ unsigned med3u(unsigned a, unsigned b, unsigned c) {
    unsigned r;
    asm("v_med3_u32 %0, %1, %2, %3" : "=v"(r) : "v"(a), "v"(b), "v"(c));
    return r;
}
// insert kb into sorted (m0<=m1<=m2<=m3): 1 min + 3 med3, all DEPTH-1 independent
#define INS4(kb) {                                                      \
    const unsigned _n3 = med3u(m2, m3, (kb));                           \
    const unsigned _n2 = med3u(m1, m2, (kb));                           \
    const unsigned _n1 = med3u(m0, m1, (kb));                           \
    const unsigned _n0 = min(m0, (kb));                                 \
    m0 = _n0; m1 = _n1; m2 = _n2; m3 = _n3; }

// ---------------- repack: weights + padded f32 atom table + batch boundaries ----
__global__ void repack_kernel(const float* __restrict__ W1, const float* __restrict__ b1,
                              const float* __restrict__ W2,
                              const float* __restrict__ y, const int* __restrict__ yb,
                              float* __restrict__ wp, float* __restrict__ ypad,
                              int* __restrict__ seg)
{
    const int tid = blockIdx.x*256 + threadIdx.x;
    const int stride = gridDim.x*256;

    for (int i = tid; i < 3*PK_LAY; i += stride) {
        const int L = i / PK_LAY, r = i % PK_LAY;
        float v;
        if (r < PK_WB) {                    // wx[o][20] = W1a(16) | b1 | w_dist | pad2
            const int o = r / 20, c = r % 20;
            if      (c < 16)  v = W1[(L*HH + o)*HH + c];
            else if (c == 16) v = b1[L*HH + o];
            else if (c == 17) v = W1[(L*HH + o)*HH + 32];
            else              v = 0.0f;
        } else if (r < PK_WT) {             // wb[o][16] = W1[o][16..31]
            const int q = r - PK_WB, o = q / 16, c = q % 16;
            v = W1[(L*HH + o)*HH + 16 + c];
        } else {                            // wt[o][16] = W2[d][o] transposed
            const int q = r - PK_WT, o = q / 16, d = q % 16;
            v = W2[(L*DD + d)*HH + o];
        }
        wp[i] = v;
    }

    // padded candidate table: [b][slot] = (-2y0,-2y1,-2y2,|y|^2), pad = +inf
    for (int p = tid; p < BB*PSLOT; p += stride) {
        const int b = p / PSLOT, o = p % PSLOT;
        int l = 0, r = M_ATM;
        while (l < r) { int m = (l+r) >> 1; if (yb[m] <  b) l = m+1; else r = m; }
        const int lo = l;
        l = 0; r = M_ATM;
        while (l < r) { int m = (l+r) >> 1; if (yb[m] <= b) l = m+1; else r = m; }
        const int hi = l;
        float4 v;
        const int j = lo + o;
        if (j < hi) {
            const double y0 = (double)y[j*3+0];
            const double y1 = (double)y[j*3+1];
            const double y2 = (double)y[j*3+2];
            v = make_float4((float)(-2.0*y0), (float)(-2.0*y1), (float)(-2.0*y2),
                            (float)(y0*y0 + y1*y1 + y2*y2));
        } else {
            v = make_float4(0.0f, 0.0f, 0.0f, __builtin_inff());
        }
        reinterpret_cast<float4*>(ypad)[p] = v;
    }

    for (int j = tid; j < M_ATM; j += stride) {
        const int bcur  = yb[j];
        const int bprev = (j == 0) ? -1 : yb[j-1];
        for (int t = bprev+1; t <= bcur; ++t) seg[t] = j;
        if (j == M_ATM-1) { for (int t = bcur+1; t <= BB; ++t) seg[t] = M_ATM; }
    }
}

__device__ __forceinline__ unsigned wave_min_u32(unsigned v) {
    v = dpp_min_u32<0xB1>(v);    // xor 1  (VALU)
    v = dpp_min_u32<0x4E>(v);    // xor 2  (VALU)
    v = dpp_min_u32<0x141>(v);   // 8-lane merge (VALU)
    v = dpp_min_u32<0x140>(v);   // 16-lane merge (VALU)
    { const unsigned o = (unsigned)__builtin_amdgcn_ds_swizzle((int)v, 0x401F);  // xor 16
      v = (o < v) ? o : v; }
    { const unsigned o = (unsigned)__shfl_xor((int)v, 32);                        // xor 32
      v = (o < v) ? o : v; }
    return v;
}

// ---------------- KNN: one WAVE per point, u32 truncated-key selection ----------
__global__ __launch_bounds__(256) void knn_kernel(
    const float* __restrict__ x, const int* __restrict__ xb,
    const float* __restrict__ ypad, const int* __restrict__ seg,
    const float* __restrict__ yg,
    int* __restrict__ out_idx, float* __restrict__ out_d2)
{
    const int wv   = threadIdx.x >> 6;
    const int lane = threadIdx.x & 63;
    const int n    = blockIdx.x * 4 + wv;

    const float xf0 = x[n*3+0], xf1 = x[n*3+1], xf2 = x[n*3+2];
    const float sxf = fmaf(xf0, xf0, fmaf(xf1, xf1, xf2*xf2));
    const int b  = xb[n];
    const int lo = seg[b];
    const float4* __restrict__ base =
        reinterpret_cast<const float4*>(ypad) + b*PSLOT + lane;

    // per-lane sorted top-4 keys: med3 insert, fully unrolled (loads batch-issue)
    unsigned m0 = SENT, m1 = SENT, m2 = SENT, m3 = SENT;
    #pragma unroll
    for (int s = 0; s < SLOTS; ++s) {
        const float4 q = base[64*s];
        float dd = fmaf(xf2, q.z, fmaf(xf1, q.y, fmaf(xf0, q.x, sxf + q.w)));
        dd = fmaxf(dd, 0.0f);
        const unsigned kb = (__float_as_uint(dd) & 0xFFFFF000u)
                          | (unsigned)(lane | (s << 6));
        INS4(kb)
    }

    unsigned long long cmask = 0ull;   // consumed slots (for rare rebuild)
    unsigned res_key = 0, h16 = 0;

    #define POPWIN(H)                                                         \
        if (lane == ((H) & 63u)) {                                            \
            cmask |= 1ull << (((H) >> 6) & 63u);                              \
            m0 = m1; m1 = m2; m2 = m3; m3 = SENT;                             \
            if (m0 == SENT) {                                                 \
                _Pragma("unroll 1")                                           \
                for (int s2 = 0; s2 < SLOTS; ++s2) {                          \
                    const float4 q2 = base[64*s2];                            \
                    float d2f = fmaf(xf2, q2.z, fmaf(xf1, q2.y,               \
                                 fmaf(xf0, q2.x, sxf + q2.w)));               \
                    d2f = fmaxf(d2f, 0.0f);                                   \
                    unsigned kb2 = (__float_as_uint(d2f) & 0xFFFFF000u)       \
                                 | (unsigned)(lane | (s2 << 6));              \
                    if ((cmask >> s2) & 1ull) kb2 = SENT;                     \
                    INS4(kb2)                                                 \
                }                                                             \
            }                                                                 \
        }

    for (int r = 0; r < KK; ++r) {
        const unsigned h = wave_min_u32(m0);   // wave-uniform winner key
        if (lane == r) res_key = h;
        h16 = h;
        POPWIN(h)
    }

    // margin extras: truncation (2^-11 rel) + f32 eval error coverage
    int e = 0;
    {
        const float d16t = __uint_as_float(h16 & 0xFFFFF000u);
        const unsigned limbits = __float_as_uint(fmaf(d16t, 1.0025f, 0.01f));
        while (e < 8) {
            const unsigned h = wave_min_u32(m0);
            if ((h & 0xFFFFF000u) > limbits) break;
            if (lane == KK + e) res_key = h;
            POPWIN(h)
            ++e;
        }
    }
    #undef POPWIN

    // finalize: exact f64 distances for the 16+e survivors
    const int nact = KK + e;
    const bool have = (lane < nact);
    const unsigned off = res_key & 0xFFFu;
    double dd64 = 0.0;
    if (have) {
        const int j = lo + (int)off;
        const double yy0 = (double)yg[j*3+0];
        const double yy1 = (double)yg[j*3+1];
        const double yy2 = (double)yg[j*3+2];
        const double xd0 = (double)xf0, xd1 = (double)xf1, xd2 = (double)xf2;
        const double sxd = fma(xd0, xd0, fma(xd1, xd1, xd2*xd2));
        const double syd = fma(yy0, yy0, fma(yy1, yy1, yy2*yy2));
        dd64 = fma(xd2, -2.0*yy2, fma(xd1, -2.0*yy1, fma(xd0, -2.0*yy0, sxd + syd)));
        dd64 = fmax(dd64, 0.0);
    }

    if (e == 0) {
        if (have) {
            out_idx[n*KK + lane] = lo + (int)off;
            out_d2 [n*KK + lane] = (float)dd64;
        }
    } else {
        const unsigned long long fkey = have
            ? (((unsigned long long)__double_as_longlong(dd64) & ~0xFFFull) | off)
            : 0xFFFFFFFFFFFFFFFFull;
        int rank = 0;
        #pragma unroll 1
        for (int t = 0; t < nact; ++t) {
            const unsigned klo = (unsigned)__builtin_amdgcn_readlane((int)(unsigned)fkey, t);
            const unsigned khi = (unsigned)__builtin_amdgcn_readlane((int)(unsigned)(fkey >> 32), t);
            const unsigned long long kt = ((unsigned long long)khi << 32) | klo;
            rank += (kt < fkey) ? 1 : 0;
        }
        if (have && rank < KK) {
            out_idx[n*KK + rank] = lo + (int)off;
            out_d2 [n*KK + rank] = (float)dd64;
        }
    }
}

// ---------------- MP: 16 lanes/point, coop base + hsum-first W2, pk-FMA dots ----
#define DOT16(res, A, q0, q1, q2, q3) {                                 \
    float _e = res, _o = 0.0f;                                          \
    _e = fmaf(A[0],  q0.x, _e); _o = fmaf(A[1],  q0.y, _o);             \
    _e = fmaf(A[2],  q0.z, _e); _o = fmaf(A[3],  q0.w, _o);             \
    _e = fmaf(A[4],  q1.x, _e); _o = fmaf(A[5],  q1.y, _o);             \
    _e = fmaf(A[6],  q1.z, _e); _o = fmaf(A[7],  q1.w, _o);             \
    _e = fmaf(A[8],  q2.x, _e); _o = fmaf(A[9],  q2.y, _o);             \
    _e = fmaf(A[10], q2.z, _e); _o = fmaf(A[11], q2.w, _o);             \
    _e = fmaf(A[12], q3.x, _e); _o = fmaf(A[13], q3.y, _o);             \
    _e = fmaf(A[14], q3.z, _e); _o = fmaf(A[15], q3.w, _o);             \
    res = _e + _o; }

__global__ __launch_bounds__(256, 1) void mp_kernel(
    const int*   __restrict__ nidx, const float* __restrict__ nd2,
    const float* __restrict__ yat,  const float* __restrict__ wpack,
    const float* __restrict__ b2,
    const float* __restrict__ gnw, const float* __restrict__ gnb,
    float* __restrict__ out)
{
    const int g  = blockIdx.x * 256 + threadIdx.x;
    const int n  = g >> 4;
    const int kl = g & 15;     // lane's k AND lane's output channel

    const int   idx  = nidx[n*KK + kl];
    const float dist = nd2 [n*KK + kl];

    float at[DD];
    f32x2 at2[8];              // packed once, reused 99x in the inner loops
    {
        const float4* p0 = reinterpret_cast<const float4*>(yat + (long)idx*DD);
        const float4 a = p0[0], b = p0[1], c = p0[2], d = p0[3];
        at[0]=a.x;  at[1]=a.y;  at[2]=a.z;  at[3]=a.w;
        at[4]=b.x;  at[5]=b.y;  at[6]=b.z;  at[7]=b.w;
        at[8]=c.x;  at[9]=c.y;  at[10]=c.z; at[11]=c.w;
        at[12]=d.x; at[13]=d.y; at[14]=d.z; at[15]=d.w;
        at2[0]=mk2(a.x,a.y); at2[1]=mk2(a.z,a.w);
        at2[2]=mk2(b.x,b.y); at2[3]=mk2(b.z,b.w);
        at2[4]=mk2(c.x,c.y); at2[5]=mk2(c.z,c.w);
        at2[6]=mk2(d.x,d.y); at2[7]=mk2(d.z,d.w);
    }

    float pe[DD];
    #pragma unroll
    for (int h = 0; h < DD; ++h) pe[h] = 1.0f;
    float pe_own = 1.0f;

    for (int L = 0; L < 3; ++L) {
        const float* wx = wpack + L*PK_LAY + PK_WX;   // [o][20]
        const float* wb = wpack + L*PK_LAY + PK_WB;   // [o][16] (uniform use)
        const float* wt = wpack + L*PK_LAY + PK_WT;   // [o][16] (col kl per lane)

        // W2 column for own channel: w2r[o] = W2[kl][o]
        float w2r[HH];
        #pragma unroll
        for (int o = 0; o < HH; ++o) w2r[o] = wt[o*16 + kl];

        // cooperative base: lane owns rows kl and kl+16; row 32 uniform
        float baseA, baseB, base32;
        {
            const float4* ra = reinterpret_cast<const float4*>(wx + kl*20);
            const float4 a0 = ra[0], a1 = ra[1], a2 = ra[2], a3 = ra[3], a4 = ra[4];
            float t = a4.x; DOT16(t, pe, a0, a1, a2, a3); baseA = t;
            const float4* rb = reinterpret_cast<const float4*>(wx + (kl+16)*20);
            const float4 b0 = rb[0], b1_ = rb[1], b2_ = rb[2], b3 = rb[3], b4 = rb[4];
            t = b4.x; DOT16(t, pe, b0, b1_, b2_, b3); baseB = t;
            const float4* rc = reinterpret_cast<const float4*>(wx + 32*20);
            const float4 c0 = rc[0], c1 = rc[1], c2 = rc[2], c3 = rc[3], c4 = rc[4];
            t = c4.x; DOT16(t, pe, c0, c1, c2, c3); base32 = t;
        }

        // hoisted broadcasts: all independent ds_swizzles, latency overlapped
        float bo[HH];
        #define BC(i) bo[i] = bc16<i>(baseA); bo[16+(i)] = bc16<i>(baseB);
        BC(0)  BC(1)  BC(2)  BC(3)  BC(4)  BC(5)  BC(6)  BC(7)
        BC(8)  BC(9)  BC(10) BC(11) BC(12) BC(13) BC(14) BC(15)
        #undef BC
        bo[32] = base32;

        float msg_d = 16.0f * b2[L*DD + kl];

        // inner loop: packed at-dot (8 pk_fma = 16 FMAs in 8 issue slots)
        #pragma unroll
        for (int o = 0; o < HH; ++o) {
            const float wd = wx[o*20 + 17];                       // uniform
            const float4* wr = reinterpret_cast<const float4*>(wb + o*16);
            const float4 y0 = wr[0], y1 = wr[1], y2 = wr[2], y3 = wr[3];
            f32x2 acc = mk2(fmaf(dist, wd, bo[o]), 0.0f);
            pkfma(acc, at2[0], mk2(y0.x, y0.y));
            pkfma(acc, at2[1], mk2(y0.z, y0.w));
            pkfma(acc, at2[2], mk2(y1.x, y1.y));
            pkfma(acc, at2[3], mk2(y1.z, y1.w));
            pkfma(acc, at2[4], mk2(y2.x, y2.y));
            pkfma(acc, at2[5], mk2(y2.z, y2.w));
            pkfma(acc, at2[6], mk2(y3.x, y3.y));
            pkfma(acc, at2[7], mk2(y3.z, y3.w));
            const float u = acc.x + acc.y;
            float hs = fmaxf(u, SLOPE*u);          // leaky per-k
            hs = dpp_sum16(hs);                    // sum over the point's 16 k's
            msg_d = fmaf(hs, w2r[o], msg_d);       // own channel only
        }

        // GroupNorm(2,16): lane owns channel kl; group = kl>>3 (8 lanes, DPP)
        const float mu = dpp_sum8(msg_d) * 0.125f;
        const float dvn = msg_d - mu;
        const float var = dpp_sum8(dvn * dvn) * 0.125f;
        const float rs = rsqrtf(var + EPSGN);
        const float v = dvn * rs * gnw[L*DD + kl] + gnb[L*DD + kl];
        pe_own += fmaxf(v, SLOPE * v);

        // rebuild replicated pe[16] for next layer's base phase
        #define PEB(i) pe[i] = bc16<i>(pe_own);
        PEB(0)  PEB(1)  PEB(2)  PEB(3)  PEB(4)  PEB(5)  PEB(6)  PEB(7)
        PEB(8)  PEB(9)  PEB(10) PEB(11) PEB(12) PEB(13) PEB(14) PEB(15)
        #undef PEB
    }

    if (kl == 0) {
        float4* op = reinterpret_cast<float4*>(out + (long)n*DD);
        op[0] = make_float4(pe[0],  pe[1],  pe[2],  pe[3]);
        op[1] = make_float4(pe[4],  pe[5],  pe[6],  pe[7]);
        op[2] = make_float4(pe[8],  pe[9],  pe[10], pe[11]);
        op[3] = make_float4(pe[12], pe[13], pe[14], pe[15]);
    }
}

extern "C" void kernel_launch(void* const* d_in, const int* in_sizes, int n_in,
                              void* d_out, int out_size, void* d_ws, size_t ws_size,
                              hipStream_t stream) {
    const float* x   = (const float*)d_in[0];
    const float* y   = (const float*)d_in[1];
    const float* yat = (const float*)d_in[2];
    const int*   xb  = (const int*)  d_in[3];
    const int*   yb  = (const int*)  d_in[4];
    const float* W1  = (const float*)d_in[5];
    const float* b1  = (const float*)d_in[6];
    const float* W2  = (const float*)d_in[7];
    const float* b2  = (const float*)d_in[8];
    const float* gnw = (const float*)d_in[9];
    const float* gnb = (const float*)d_in[10];
    float* out = (float*)d_out;

    float* ypad   = (float*)((char*)d_ws + WS_PAD);
    int*   seg    = (int*)  ((char*)d_ws + WS_SEG);
    float* wpack  = (float*)((char*)d_ws + WS_WP);
    int*   ws_idx = (int*)  ((char*)d_ws + WS_IDX);
    float* ws_d2  = (float*)((char*)d_ws + WS_D2);

    repack_kernel<<<64, 256, 0, stream>>>(W1, b1, W2, y, yb, wpack, ypad, seg);
    knn_kernel<<<N_PTS/4, 256, 0, stream>>>(x, xb, ypad, seg, y, ws_idx, ws_d2);
    mp_kernel<<<(N_PTS*16)/256, 256, 0, stream>>>(
        ws_idx, ws_d2, yat, wpack, b2, gnw, gnb, out);
}

// Round 21
// 68.817 us; speedup vs baseline: 1.3273x; 1.3273x over previous
//
#include <hip/hip_runtime.h>
#include <math.h>

#define N_PTS 20000
#define M_ATM 8000
#define DD    16
#define KK    16
#define HH    33
#define BB    4
#define EPSGN 1e-5f
#define SLOPE 0.2f
#define SLOTS 36          // 36*64 = 2304 candidate slots per batch
#define PSLOT 2304
#define SENT  0xFFFFFFFFu // > any real key (real off <= 2303 < 0xFFF)

// packed layout per layer (floats): wx[33][20] | wb[33][16] | wt[33][16]
#define PK_WX   0
#define PK_WB   660
#define PK_WT   1188
#define PK_LAY  1716

// ws layout (bytes)
#define WS_PAD   0                      // 4*2304*16 = 147456 (padded f32 atom table)
#define WS_SEG   147456                 // 8 ints
#define WS_WP    147520                 // 3*1716 floats -> ends 168112
#define WS_IDX   168128                 // N*K ints
#define WS_D2    (168128 + 1280000)     // N*K floats

// ---- DPP cross-lane helpers (VALU pipe, ~4cyc latency vs ~35 for ds_swizzle) ----
template<int CTRL> __device__ __forceinline__ float dpp_addf(float v) {
    return v + __int_as_float(__builtin_amdgcn_update_dpp(
        0, __float_as_int(v), CTRL, 0xF, 0xF, true));
}
__device__ __forceinline__ float dpp_sum16(float v) {
    v = dpp_addf<0xB1>(v);    // quad_perm xor1
    v = dpp_addf<0x4E>(v);    // quad_perm xor2
    v = dpp_addf<0x141>(v);   // row_half_mirror
    v = dpp_addf<0x140>(v);   // row_mirror
    return v;
}
__device__ __forceinline__ float dpp_sum8(float v) {
    v = dpp_addf<0xB1>(v);
    v = dpp_addf<0x4E>(v);
    v = dpp_addf<0x141>(v);
    return v;
}
// broadcast lane O (0..15) within each 16-lane group (BitMode swizzle)
template<int O> __device__ __forceinline__ float bc16(float v) {
    return __int_as_float(__builtin_amdgcn_ds_swizzle(
        __float_as_int(v), (O << 5) | 0x10));
}
template<int CTRL> __device__ __forceinline__ unsigned dpp_min_u32(unsigned v) {
    const unsigned o = (unsigned)__builtin_amdgcn_update_dpp(
        (int)v, (int)v, CTRL, 0xF, 0xF, false);
    return (o < v) ? o : v;
}
// median of 3 u32 (single VOP3) -- sorted-insert building block
__device__ __forceinline__ unsigned med3u(unsigned a, unsigned b, unsigned c) {
    unsigned r;
    asm("v_med3_u32 %0, %1, %2, %3" : "=v"(r) : "v"(a), "v"(b), "v"(c));
    return r;
}
// insert kb into sorted (m0<=m1<=m2<=m3): 1 min + 3 med3, all DEPTH-1 independent
#define INS4(kb) {                                                      \
    const unsigned _n3 = med3u(m2, m3, (kb));                           \
    const unsigned _n2 = med3u(m1, m2, (kb));                           \
    const unsigned _n1 = med3u(m0, m1, (kb));                           \
    const unsigned _n0 = min(m0, (kb));                                 \
    m0 = _n0; m1 = _n1; m2 = _n2; m3 = _n3; }

// ---------------- repack: weights + padded f32 atom table + batch boundaries ----
__global__ void repack_kernel(const float* __restrict__ W1, const float* __restrict__ b1,
                              const float* __restrict__ W2,
                              const float* __restrict__ y, const int* __restrict__ yb,
                              float* __restrict__ wp, float* __restrict__ ypad,
                              int* __restrict__ seg)
{
    const int tid = blockIdx.x*256 + threadIdx.x;
    const int stride = gridDim.x*256;

    for (int i = tid; i < 3*PK_LAY; i += stride) {
        const int L = i / PK_LAY, r = i % PK_LAY;
        float v;
        if (r < PK_WB) {                    // wx[o][20] = W1a(16) | b1 | w_dist | pad2
            const int o = r / 20, c = r % 20;
            if      (c < 16)  v = W1[(L*HH + o)*HH + c];
            else if (c == 16) v = b1[L*HH + o];
            else if (c == 17) v = W1[(L*HH + o)*HH + 32];
            else              v = 0.0f;
        } else if (r < PK_WT) {             // wb[o][16] = W1[o][16..31]
            const int q = r - PK_WB, o = q / 16, c = q % 16;
            v = W1[(L*HH + o)*HH + 16 + c];
        } else {                            // wt[o][16] = W2[d][o] transposed
            const int q = r - PK_WT, o = q / 16, d = q % 16;
            v = W2[(L*DD + d)*HH + o];
        }
        wp[i] = v;
    }

    // padded candidate table: [b][slot] = (-2y0,-2y1,-2y2,|y|^2), pad = +inf
    for (int p = tid; p < BB*PSLOT; p += stride) {
        const int b = p / PSLOT, o = p % PSLOT;
        int l = 0, r = M_ATM;
        while (l < r) { int m = (l+r) >> 1; if (yb[m] <  b) l = m+1; else r = m; }
        const int lo = l;
        l = 0; r = M_ATM;
        while (l < r) { int m = (l+r) >> 1; if (yb[m] <= b) l = m+1; else r = m; }
        const int hi = l;
        float4 v;
        const int j = lo + o;
        if (j < hi) {
            const double y0 = (double)y[j*3+0];
            const double y1 = (double)y[j*3+1];
            const double y2 = (double)y[j*3+2];
            v = make_float4((float)(-2.0*y0), (float)(-2.0*y1), (float)(-2.0*y2),
                            (float)(y0*y0 + y1*y1 + y2*y2));
        } else {
            v = make_float4(0.0f, 0.0f, 0.0f, __builtin_inff());
        }
        reinterpret_cast<float4*>(ypad)[p] = v;
    }

    for (int j = tid; j < M_ATM; j += stride) {
        const int bcur  = yb[j];
        const int bprev = (j == 0) ? -1 : yb[j-1];
        for (int t = bprev+1; t <= bcur; ++t) seg[t] = j;
        if (j == M_ATM-1) { for (int t = bcur+1; t <= BB; ++t) seg[t] = M_ATM; }
    }
}

__device__ __forceinline__ unsigned wave_min_u32(unsigned v) {
    v = dpp_min_u32<0xB1>(v);    // xor 1  (VALU)
    v = dpp_min_u32<0x4E>(v);    // xor 2  (VALU)
    v = dpp_min_u32<0x141>(v);   // 8-lane merge (VALU)
    v = dpp_min_u32<0x140>(v);   // 16-lane merge (VALU)
    { const unsigned o = (unsigned)__builtin_amdgcn_ds_swizzle((int)v, 0x401F);  // xor 16
      v = (o < v) ? o : v; }
    { const unsigned o = (unsigned)__shfl_xor((int)v, 32);                        // xor 32
      v = (o < v) ? o : v; }
    return v;
}

// ---------------- KNN: one WAVE per point, u32 truncated-key selection ----------
__global__ __launch_bounds__(256) void knn_kernel(
    const float* __restrict__ x, const int* __restrict__ xb,
    const float* __restrict__ ypad, const int* __restrict__ seg,
    const float* __restrict__ yg,
    int* __restrict__ out_idx, float* __restrict__ out_d2)
{
    const int wv   = threadIdx.x >> 6;
    const int lane = threadIdx.x & 63;
    const int n    = blockIdx.x * 4 + wv;

    const float xf0 = x[n*3+0], xf1 = x[n*3+1], xf2 = x[n*3+2];
    const float sxf = fmaf(xf0, xf0, fmaf(xf1, xf1, xf2*xf2));
    const int b  = xb[n];
    const int lo = seg[b];
    const float4* __restrict__ base =
        reinterpret_cast<const float4*>(ypad) + b*PSLOT + lane;

    // per-lane sorted top-4 keys: med3 insert, fully unrolled (loads batch-issue)
    unsigned m0 = SENT, m1 = SENT, m2 = SENT, m3 = SENT;
    #pragma unroll
    for (int s = 0; s < SLOTS; ++s) {
        const float4 q = base[64*s];
        float dd = fmaf(xf2, q.z, fmaf(xf1, q.y, fmaf(xf0, q.x, sxf + q.w)));
        dd = fmaxf(dd, 0.0f);
        const unsigned kb = (__float_as_uint(dd) & 0xFFFFF000u)
                          | (unsigned)(lane | (s << 6));
        INS4(kb)
    }

    unsigned long long cmask = 0ull;   // consumed slots (for rare rebuild)
    unsigned res_key = 0, h16 = 0;

    #define POPWIN(H)                                                         \
        if (lane == ((H) & 63u)) {                                            \
            cmask |= 1ull << (((H) >> 6) & 63u);                              \
            m0 = m1; m1 = m2; m2 = m3; m3 = SENT;                             \
            if (m0 == SENT) {                                                 \
                _Pragma("unroll 1")                                           \
                for (int s2 = 0; s2 < SLOTS; ++s2) {                          \
                    const float4 q2 = base[64*s2];                            \
                    float d2f = fmaf(xf2, q2.z, fmaf(xf1, q2.y,               \
                                 fmaf(xf0, q2.x, sxf + q2.w)));               \
                    d2f = fmaxf(d2f, 0.0f);                                   \
                    unsigned kb2 = (__float_as_uint(d2f) & 0xFFFFF000u)       \
                                 | (unsigned)(lane | (s2 << 6));              \
                    if ((cmask >> s2) & 1ull) kb2 = SENT;                     \
                    INS4(kb2)                                                 \
                }                                                             \
            }                                                                 \
        }

    for (int r = 0; r < KK; ++r) {
        const unsigned h = wave_min_u32(m0);   // wave-uniform winner key
        if (lane == r) res_key = h;
        h16 = h;
        POPWIN(h)
    }

    // margin extras: truncation (2^-11 rel) + f32 eval error coverage
    int e = 0;
    {
        const float d16t = __uint_as_float(h16 & 0xFFFFF000u);
        const unsigned limbits = __float_as_uint(fmaf(d16t, 1.0025f, 0.01f));
        while (e < 8) {
            const unsigned h = wave_min_u32(m0);
            if ((h & 0xFFFFF000u) > limbits) break;
            if (lane == KK + e) res_key = h;
            POPWIN(h)
            ++e;
        }
    }
    #undef POPWIN

    // finalize: exact f64 distances for the 16+e survivors
    const int nact = KK + e;
    const bool have = (lane < nact);
    const unsigned off = res_key & 0xFFFu;
    double dd64 = 0.0;
    if (have) {
        const int j = lo + (int)off;
        const double yy0 = (double)yg[j*3+0];
        const double yy1 = (double)yg[j*3+1];
        const double yy2 = (double)yg[j*3+2];
        const double xd0 = (double)xf0, xd1 = (double)xf1, xd2 = (double)xf2;
        const double sxd = fma(xd0, xd0, fma(xd1, xd1, xd2*xd2));
        const double syd = fma(yy0, yy0, fma(yy1, yy1, yy2*yy2));
        dd64 = fma(xd2, -2.0*yy2, fma(xd1, -2.0*yy1, fma(xd0, -2.0*yy0, sxd + syd)));
        dd64 = fmax(dd64, 0.0);
    }

    if (e == 0) {
        if (have) {
            out_idx[n*KK + lane] = lo + (int)off;
            out_d2 [n*KK + lane] = (float)dd64;
        }
    } else {
        const unsigned long long fkey = have
            ? (((unsigned long long)__double_as_longlong(dd64) & ~0xFFFull) | off)
            : 0xFFFFFFFFFFFFFFFFull;
        int rank = 0;
        #pragma unroll 1
        for (int t = 0; t < nact; ++t) {
            const unsigned klo = (unsigned)__builtin_amdgcn_readlane((int)(unsigned)fkey, t);
            const unsigned khi = (unsigned)__builtin_amdgcn_readlane((int)(unsigned)(fkey >> 32), t);
            const unsigned long long kt = ((unsigned long long)khi << 32) | klo;
            rank += (kt < fkey) ? 1 : 0;
        }
        if (have && rank < KK) {
            out_idx[n*KK + rank] = lo + (int)off;
            out_d2 [n*KK + rank] = (float)dd64;
        }
    }
}

// ---------------- MP: 16 lanes/point, coop base + hsum-first W2, DPP reductions --
#define DOT16(res, A, q0, q1, q2, q3) {                                 \
    float _e = res, _o = 0.0f;                                          \
    _e = fmaf(A[0],  q0.x, _e); _o = fmaf(A[1],  q0.y, _o);             \
    _e = fmaf(A[2],  q0.z, _e); _o = fmaf(A[3],  q0.w, _o);             \
    _e = fmaf(A[4],  q1.x, _e); _o = fmaf(A[5],  q1.y, _o);             \
    _e = fmaf(A[6],  q1.z, _e); _o = fmaf(A[7],  q1.w, _o);             \
    _e = fmaf(A[8],  q2.x, _e); _o = fmaf(A[9],  q2.y, _o);             \
    _e = fmaf(A[10], q2.z, _e); _o = fmaf(A[11], q2.w, _o);             \
    _e = fmaf(A[12], q3.x, _e); _o = fmaf(A[13], q3.y, _o);             \
    _e = fmaf(A[14], q3.z, _e); _o = fmaf(A[15], q3.w, _o);             \
    res = _e + _o; }

__global__ __launch_bounds__(256, 1) void mp_kernel(
    const int*   __restrict__ nidx, const float* __restrict__ nd2,
    const float* __restrict__ yat,  const float* __restrict__ wpack,
    const float* __restrict__ b2,
    const float* __restrict__ gnw, const float* __restrict__ gnb,
    float* __restrict__ out)
{
    const int g  = blockIdx.x * 256 + threadIdx.x;
    const int n  = g >> 4;
    const int kl = g & 15;     // lane's k AND lane's output channel

    const int   idx  = nidx[n*KK + kl];
    const float dist = nd2 [n*KK + kl];

    float at[DD];
    {
        const float4* p0 = reinterpret_cast<const float4*>(yat + (long)idx*DD);
        const float4 a = p0[0], b = p0[1], c = p0[2], d = p0[3];
        at[0]=a.x;  at[1]=a.y;  at[2]=a.z;  at[3]=a.w;
        at[4]=b.x;  at[5]=b.y;  at[6]=b.z;  at[7]=b.w;
        at[8]=c.x;  at[9]=c.y;  at[10]=c.z; at[11]=c.w;
        at[12]=d.x; at[13]=d.y; at[14]=d.z; at[15]=d.w;
    }

    float pe[DD];
    #pragma unroll
    for (int h = 0; h < DD; ++h) pe[h] = 1.0f;
    float pe_own = 1.0f;

    for (int L = 0; L < 3; ++L) {
        const float* wx = wpack + L*PK_LAY + PK_WX;   // [o][20]
        const float* wb = wpack + L*PK_LAY + PK_WB;   // [o][16] (uniform use)
        const float* wt = wpack + L*PK_LAY + PK_WT;   // [o][16] (col kl per lane)

        // W2 column for own channel: w2r[o] = W2[kl][o]
        float w2r[HH];
        #pragma unroll
        for (int o = 0; o < HH; ++o) w2r[o] = wt[o*16 + kl];

        // cooperative base: lane owns rows kl and kl+16; row 32 uniform
        float baseA, baseB, base32;
        {
            const float4* ra = reinterpret_cast<const float4*>(wx + kl*20);
            const float4 a0 = ra[0], a1 = ra[1], a2 = ra[2], a3 = ra[3], a4 = ra[4];
            float t = a4.x; DOT16(t, pe, a0, a1, a2, a3); baseA = t;
            const float4* rb = reinterpret_cast<const float4*>(wx + (kl+16)*20);
            const float4 b0 = rb[0], b1_ = rb[1], b2_ = rb[2], b3 = rb[3], b4 = rb[4];
            t = b4.x; DOT16(t, pe, b0, b1_, b2_, b3); baseB = t;
            const float4* rc = reinterpret_cast<const float4*>(wx + 32*20);
            const float4 c0 = rc[0], c1 = rc[1], c2 = rc[2], c3 = rc[3], c4 = rc[4];
            t = c4.x; DOT16(t, pe, c0, c1, c2, c3); base32 = t;
        }

        // hoisted broadcasts: all independent ds_swizzles, latency overlapped
        float bo[HH];
        #define BC(i) bo[i] = bc16<i>(baseA); bo[16+(i)] = bc16<i>(baseB);
        BC(0)  BC(1)  BC(2)  BC(3)  BC(4)  BC(5)  BC(6)  BC(7)
        BC(8)  BC(9)  BC(10) BC(11) BC(12) BC(13) BC(14) BC(15)
        #undef BC
        bo[32] = base32;

        float msg_d = 16.0f * b2[L*DD + kl];

        // pure-VALU inner loop: dist FMA + at-dot + leaky + 4 DPP adds + W2 FMA
        #pragma unroll
        for (int o = 0; o < HH; ++o) {
            const float wd = wx[o*20 + 17];                       // uniform
            const float4* wr = reinterpret_cast<const float4*>(wb + o*16);
            const float4 y0 = wr[0], y1 = wr[1], y2 = wr[2], y3 = wr[3];
            float u = fmaf(dist, wd, bo[o]);
            DOT16(u, at, y0, y1, y2, y3);
            float hs = fmaxf(u, SLOPE*u);          // leaky per-k
            hs = dpp_sum16(hs);                    // sum over the point's 16 k's
            msg_d = fmaf(hs, w2r[o], msg_d);       // own channel only
        }

        // GroupNorm(2,16): lane owns channel kl; group = kl>>3 (8 lanes, DPP)
        const float mu = dpp_sum8(msg_d) * 0.125f;
        const float dvn = msg_d - mu;
        const float var = dpp_sum8(dvn * dvn) * 0.125f;
        const float rs = rsqrtf(var + EPSGN);
        const float v = dvn * rs * gnw[L*DD + kl] + gnb[L*DD + kl];
        pe_own += fmaxf(v, SLOPE * v);

        // rebuild replicated pe[16] for next layer's base phase
        #define PEB(i) pe[i] = bc16<i>(pe_own);
        PEB(0)  PEB(1)  PEB(2)  PEB(3)  PEB(4)  PEB(5)  PEB(6)  PEB(7)
        PEB(8)  PEB(9)  PEB(10) PEB(11) PEB(12) PEB(13) PEB(14) PEB(15)
        #undef PEB
    }

    if (kl == 0) {
        float4* op = reinterpret_cast<float4*>(out + (long)n*DD);
        op[0] = make_float4(pe[0],  pe[1],  pe[2],  pe[3]);
        op[1] = make_float4(pe[4],  pe[5],  pe[6],  pe[7]);
        op[2] = make_float4(pe[8],  pe[9],  pe[10], pe[11]);
        op[3] = make_float4(pe[12], pe[13], pe[14], pe[15]);
    }
}

extern "C" void kernel_launch(void* const* d_in, const int* in_sizes, int n_in,
                              void* d_out, int out_size, void* d_ws, size_t ws_size,
                              hipStream_t stream) {
    const float* x   = (const float*)d_in[0];
    const float* y   = (const float*)d_in[1];
    const float* yat = (const float*)d_in[2];
    const int*   xb  = (const int*)  d_in[3];
    const int*   yb  = (const int*)  d_in[4];
    const float* W1  = (const float*)d_in[5];
    const float* b1  = (const float*)d_in[6];
    const float* W2  = (const float*)d_in[7];
    const float* b2  = (const float*)d_in[8];
    const float* gnw = (const float*)d_in[9];
    const float* gnb = (const float*)d_in[10];
    float* out = (float*)d_out;

    float* ypad   = (float*)((char*)d_ws + WS_PAD);
    int*   seg    = (int*)  ((char*)d_ws + WS_SEG);
    float* wpack  = (float*)((char*)d_ws + WS_WP);
    int*   ws_idx = (int*)  ((char*)d_ws + WS_IDX);
    float* ws_d2  = (float*)((char*)d_ws + WS_D2);

    repack_kernel<<<64, 256, 0, stream>>>(W1, b1, W2, y, yb, wpack, ypad, seg);
    knn_kernel<<<N_PTS/4, 256, 0, stream>>>(x, xb, ypad, seg, y, ws_idx, ws_d2);
    mp_kernel<<<(N_PTS*16)/256, 256, 0, stream>>>(
        ws_idx, ws_d2, yat, wpack, b2, gnw, gnb, out);
}